// Round 10
// baseline (2754.830 us; speedup 1.0000x reference)
//
#include <hip/hip_runtime.h>
#include <hip/hip_bf16.h>
#include <hip/hip_fp16.h>

// Problem constants
#define B_   64
#define SWP  512
#define D_   768
#define W_   256     // NUM_WORDS
#define H_   256
#define G4   1024    // 4*H
#define N2   2048    // both dirs' gates
#define M_   16384   // B_*W_ rows
#define A_   8
#define KK_  4

typedef __attribute__((ext_vector_type(4))) float f32x4;
typedef __attribute__((ext_vector_type(8))) short bf16x8;
typedef _Float16 __attribute__((ext_vector_type(2))) h2_t;

// k_lstm v10 tiers (128 h2 k-pairs per gate row, 1 row per thread):
//   pairs  0..31  VGPR (32 regs)
//   pairs 32..79  LDS  (12 chunks x 4 pairs, 96 KB/block)
//   pairs 80..127 streamed per step (12 x dwordx4, 96 KB/block/step, L2-res)
#define PVC 32
#define NLC 12
#define NSC 12

__device__ __forceinline__ void gload_lds16(const void* g, void* l) {
  __builtin_amdgcn_global_load_lds((const __attribute__((address_space(1))) void*)g,
                                   (__attribute__((address_space(3))) void*)l, 16, 0, 0);
}

__device__ __forceinline__ float sigm(float x) { return 1.f / (1.f + __expf(-x)); }
__device__ __forceinline__ float tanh_(float x) { return 1.f - 2.f / (1.f + __expf(2.f * x)); }

__device__ __forceinline__ float dot2acc(h2_t w, h2_t h, float acc) {
#if __has_builtin(__builtin_amdgcn_fdot2)
  return __builtin_amdgcn_fdot2(w, h, acc, false);
#else
  return acc + (float)w[0] * (float)h[0] + (float)w[1] * (float)h[1];
#endif
}

__device__ __forceinline__ h2_t bc_h2(unsigned int v) {
  union { unsigned int u; h2_t h; } cvt;
  cvt.u = v;
  return cvt.h;
}

// K1: scatter-mean wordpieces -> words (bf16). One block per (b, word).
__global__ __launch_bounds__(256) void k_words(const float* __restrict__ emb,
                                               const int* __restrict__ mask,
                                               __hip_bfloat16* __restrict__ words) {
  const int b = blockIdx.x >> 8;
  const int w = blockIdx.x & 255;
  const int tid = threadIdx.x;
  __shared__ int m[SWP];
  m[tid] = mask[b * SWP + tid];
  m[tid + 256] = mask[b * SWP + 256 + tid];
  __syncthreads();
  int lo = 0, hi = SWP;
  while (lo < hi) { int mid = (lo + hi) >> 1; if (m[mid] < w) lo = mid + 1; else hi = mid; }
  int lo2 = lo, hi2 = SWP;
  while (lo2 < hi2) { int mid = (lo2 + hi2) >> 1; if (m[mid] < w + 1) lo2 = mid + 1; else hi2 = mid; }
  const int cnt = lo2 - lo;
  const float inv = (cnt > 0) ? 1.f / (float)cnt : 0.f;
  float s0 = 0.f, s1 = 0.f, s2 = 0.f;
  for (int s = lo; s < lo2; ++s) {
    const float* row = emb + ((size_t)b * SWP + s) * D_;
    s0 += row[tid]; s1 += row[tid + 256]; s2 += row[tid + 512];
  }
  __hip_bfloat16* o = words + ((size_t)b * W_ + w) * D_;
  o[tid]       = __float2bfloat16(s0 * inv);
  o[tid + 256] = __float2bfloat16(s1 * inv);
  o[tid + 512] = __float2bfloat16(s2 * inv);
}

// K2a: concat+convert input weights to bf16 [2048][768]; fused bias b_ih+b_hh [2048]
__global__ __launch_bounds__(256) void k_prep_wih(const float* __restrict__ wf, const float* __restrict__ wr,
                                                  const float* __restrict__ bihf, const float* __restrict__ bhhf,
                                                  const float* __restrict__ bihr, const float* __restrict__ bhhr,
                                                  __hip_bfloat16* __restrict__ wih, float* __restrict__ bias) {
  const int i = blockIdx.x * 256 + threadIdx.x;
  const int n = i / D_;
  const int k = i - n * D_;
  const float v = (n < G4) ? wf[n * D_ + k] : wr[(n - G4) * D_ + k];
  wih[i] = __float2bfloat16(v);
  if (i < N2) {
    bias[i] = (i < G4) ? (bihf[i] + bhhf[i]) : (bihr[i - G4] + bhhr[i - G4]);
  }
}

// K2b: repack w_hh as half2 [dir][128 kk][1024 r]
__global__ __launch_bounds__(256) void k_prep_whh(const float* __restrict__ whf,
                                                  const float* __restrict__ whr,
                                                  h2_t* __restrict__ whhP) {
  const int i = blockIdx.x * 256 + threadIdx.x;   // 2*128*1024
  const int d = i >> 17;
  const int kk = (i >> 10) & 127;
  const int r = i & 1023;
  const float* w = d ? whr : whf;
  h2_t v;
  v[0] = (_Float16)w[r * H_ + 2 * kk];
  v[1] = (_Float16)w[r * H_ + 2 * kk + 1];
  whhP[i] = v;
}

// K2c: pack streamed tier: wstr[(d*2+uh)][c][t] = pairs 80+4c..83+4c of row r(t)
//   r(t) = (t>>7)*256 + uh*128 + (t&127)
__global__ __launch_bounds__(256) void k_prep_wstr(const h2_t* __restrict__ whhP,
                                                   f32x4* __restrict__ wstr) {
  const int i = blockIdx.x * 256 + threadIdx.x;   // 2*2*12*512
  if (i >= 2 * 2 * NSC * 512) return;
  const int t = i & 511;
  const int c = (i >> 9) % NSC;
  const int duh = i / (NSC * 512);
  const int d = duh >> 1;
  const int uh = duh & 1;
  const int r = (t >> 7) * 256 + uh * 128 + (t & 127);
  const h2_t* wp = whhP + (size_t)d * (128 * 1024);
  f32x4 v;
#pragma unroll
  for (int q = 0; q < 4; ++q)
    ((h2_t*)&v)[q] = wp[(80 + 4 * c + q) * 1024 + r];
  wstr[i] = v;
}

// K2d: zero exchange flags (every launch, before k_lstm)
__global__ __launch_bounds__(256) void k_zero_flags(int* __restrict__ flags) {
  flags[threadIdx.x] = 0;
}

// K3: xg = words @ W_ih^T + (b_ih + b_hh), bf16 MFMA, 128x128 tile, out f16
__global__ __launch_bounds__(256) void k_gemm_xg(const __hip_bfloat16* __restrict__ A,
                                                 const __hip_bfloat16* __restrict__ Wt,
                                                 const float* __restrict__ bias,
                                                 _Float16* __restrict__ C) {
  const int bm = blockIdx.y * 128;
  const int bn = blockIdx.x * 128;
  __shared__ __hip_bfloat16 As[128 * 32];
  __shared__ __hip_bfloat16 Bs[128 * 32];
  const int tid = threadIdx.x;
  const int lane = tid & 63;
  const int wave = tid >> 6;
  const int wm = (wave >> 1) * 64;
  const int wn = (wave & 1) * 64;
  const int l15 = lane & 15;
  const int l4 = lane >> 4;
  const int row_a = tid >> 2;
  const int chunk = tid & 3;
  f32x4 acc[4][4] = {};
  for (int k0 = 0; k0 < D_; k0 += 32) {
    const __hip_bfloat16* ga  = A  + (size_t)(bm + row_a) * D_ + k0 + chunk * 8;
    const __hip_bfloat16* ga2 = A  + (size_t)(bm + 64 + row_a) * D_ + k0 + chunk * 8;
    const __hip_bfloat16* gb  = Wt + (size_t)(bn + row_a) * D_ + k0 + chunk * 8;
    const __hip_bfloat16* gb2 = Wt + (size_t)(bn + 64 + row_a) * D_ + k0 + chunk * 8;
    gload_lds16(ga,  As + tid * 8);
    gload_lds16(ga2, As + 2048 + tid * 8);
    gload_lds16(gb,  Bs + tid * 8);
    gload_lds16(gb2, Bs + 2048 + tid * 8);
    __syncthreads();
    bf16x8 af[4], bf[4];
#pragma unroll
    for (int i = 0; i < 4; ++i) {
      af[i] = *(const bf16x8*)(As + (wm + i * 16 + l15) * 32 + l4 * 8);
      bf[i] = *(const bf16x8*)(Bs + (wn + i * 16 + l15) * 32 + l4 * 8);
    }
#pragma unroll
    for (int i = 0; i < 4; ++i)
#pragma unroll
      for (int j = 0; j < 4; ++j)
        acc[i][j] = __builtin_amdgcn_mfma_f32_16x16x32_bf16(af[i], bf[j], acc[i][j], 0, 0, 0);
    __syncthreads();
  }
#pragma unroll
  for (int i = 0; i < 4; ++i) {
    const int m = bm + wm + i * 16 + l4 * 4;
#pragma unroll
    for (int j = 0; j < 4; ++j) {
      const int n = bn + wn + j * 16 + l15;
      const float bs = bias[n];
#pragma unroll
      for (int r = 0; r < 4; ++r)
        C[(size_t)(m + r) * N2 + n] = (_Float16)(acc[i][j][r] + bs);
    }
  }
}

// K4 v10: 2-way unit-split BiLSTM. 256 blocks (1/CU, all co-resident: 98KB LDS).
// Block (p=bid&127, uh=bid>>7): d=p&1, b=p>>1, units uh*128..+127.
// Thread t: gate row r = (t>>7)*256 + uh*128 + (t&127)  (one row/thread).
// Tiers: 32 pairs VGPR / 48 LDS / 48 streamed. h via readlane from 2 b32.
// Cross-half h exchange each step: release-flag + acquire-spin through L2/L3.
__global__ __launch_bounds__(512)
void k_lstm(const _Float16* __restrict__ xg,    // [M_][2048]
            const h2_t* __restrict__ whhP,      // [2][128][1024]
            const f32x4* __restrict__ wstr,     // [4][12][512]
            unsigned* __restrict__ hx,          // [256][64] u32 (2 f16 each)
            int* __restrict__ flags,            // [256]
            float* __restrict__ out) {          // [B_][W_][512]
  const int bid = blockIdx.x;
  const int p = bid & 127;
  const int uh = bid >> 7;
  const int d = p & 1;
  const int b = p >> 1;
  const int t = threadIdx.x;
  const int g = t >> 7;           // gate 0:i 1:f 2:g 3:o
  const int us = t & 127;
  const int u = uh * 128 + us;
  const int r = g * 256 + u;
  const int l = t & 63;
  const int myidx = p * 2 + uh;
  const int paidx = p * 2 + (uh ^ 1);

  __shared__ __align__(16) _Float16 hbuf[256];
  __shared__ __align__(16) h2_t wlds[NLC][512][4];   // 96 KB, pairs 32..79
  __shared__ float gbuf[3][128];

  const h2_t* wp = whhP + (size_t)d * (128 * 1024);
  const f32x4* wsp = wstr + (size_t)(d * 2 + uh) * (NSC * 512);

  // VGPR tier: pairs 0..31 of own row
  unsigned wv[PVC];
#pragma unroll
  for (int j = 0; j < PVC; ++j)
    wv[j] = *(const unsigned*)&wp[j * 1024 + r];
  // LDS tier: chunk c holds pairs 32+4c..35+4c of own row
#pragma unroll
  for (int c = 0; c < NLC; ++c) {
    f32x4 v;
#pragma unroll
    for (int q = 0; q < 4; ++q)
      ((h2_t*)&v)[q] = wp[(PVC + 4 * c + q) * 1024 + r];
    *(f32x4*)&wlds[c][t][0] = v;
  }
  if (t < 256) hbuf[t] = (_Float16)0.f;
  __syncthreads();

  float c_state = 0.f;
#pragma unroll 1
  for (int step = 0; step < W_; ++step) {
    const int tt = d ? (W_ - 1 - step) : step;
    const float xv = (float)xg[((size_t)b * W_ + tt) * N2 + d * G4 + r];
    float a = 0.f, a2 = 0.f;
    if (step > 0) {
      // issue ALL stream loads first (independent; latency hides under tiers)
      f32x4 sw[NSC];
#pragma unroll
      for (int c = 0; c < NSC; ++c) sw[c] = wsp[c * 512 + t];
      const unsigned hA = *(const unsigned*)&hbuf[2 * l];        // pairs 0..63
      const unsigned hB = *(const unsigned*)&hbuf[128 + 2 * l];  // pairs 64..127
      // VGPR tier: pairs 0..31
#pragma unroll
      for (int j = 0; j < PVC; ++j) {
        const h2_t hq = bc_h2(__builtin_amdgcn_readlane(hA, j));
        if (j & 1) a2 = dot2acc(bc_h2(wv[j]), hq, a2);
        else       a  = dot2acc(bc_h2(wv[j]), hq, a);
      }
      // LDS tier: pairs 32..79
#pragma unroll
      for (int c = 0; c < NLC; ++c) {
        const f32x4 wchunk = *(const f32x4*)&wlds[c][t][0];
        const h2_t* wc = (const h2_t*)&wchunk;
#pragma unroll
        for (int q = 0; q < 4; ++q) {
          const int pp = PVC + 4 * c + q;
          const h2_t hq = bc_h2((pp < 64) ? __builtin_amdgcn_readlane(hA, pp)
                                          : __builtin_amdgcn_readlane(hB, pp - 64));
          if (q & 1) a2 = dot2acc(wc[q], hq, a2);
          else       a  = dot2acc(wc[q], hq, a);
        }
      }
      // stream tier: pairs 80..127 (all from hB)
#pragma unroll
      for (int c = 0; c < NSC; ++c) {
        const h2_t* wc = (const h2_t*)&sw[c];
#pragma unroll
        for (int q = 0; q < 4; ++q) {
          const int pp = 80 + 4 * c + q;
          const h2_t hq = bc_h2(__builtin_amdgcn_readlane(hB, pp - 64));
          if (q & 1) a2 = dot2acc(wc[q], hq, a2);
          else       a  = dot2acc(wc[q], hq, a);
        }
      }
    }
    const float av = a + a2 + xv;
    if (g) gbuf[g - 1][us] = av;
    __syncthreads();   // bar1: gbuf ready
    if (!g) {
      const float ig = sigm(av);
      const float fg = sigm(gbuf[0][us]);
      const float gg = tanh_(gbuf[1][us]);
      const float og = sigm(gbuf[2][us]);
      c_state = fg * c_state + ig * gg;
      const float h = og * tanh_(c_state);
      out[((size_t)b * W_ + tt) * 512 + d * 256 + u] = h;
      hbuf[u] = (_Float16)h;
    }
    __syncthreads();   // bar2: own-half hbuf visible to all
    if (step < W_ - 1) {
      if (t < 64) {
        // publish own half (64 u32 = 128 f16), release, then spin on partner
        const unsigned pk = *(const unsigned*)&hbuf[uh * 128 + 2 * l];
        __hip_atomic_store(&hx[myidx * 64 + l], pk, __ATOMIC_RELAXED,
                           __HIP_MEMORY_SCOPE_AGENT);
        __threadfence();
        if (t == 0)
          __hip_atomic_store(&flags[myidx], step + 1, __ATOMIC_RELEASE,
                             __HIP_MEMORY_SCOPE_AGENT);
        int v;
        do {
          v = __hip_atomic_load(&flags[paidx], __ATOMIC_ACQUIRE,
                                __HIP_MEMORY_SCOPE_AGENT);
        } while (v <= step);
        const unsigned pk2 = __hip_atomic_load(&hx[paidx * 64 + l], __ATOMIC_RELAXED,
                                               __HIP_MEMORY_SCOPE_AGENT);
        *(unsigned*)&hbuf[(uh ^ 1) * 128 + 2 * l] = pk2;
      }
      __syncthreads(); // bar3: partner half in hbuf
    }
  }
}

// K5: sent-mean + aspect gather-mean + fc1(relu) + fc2. One block per batch.
__global__ __launch_bounds__(256) void k_head(const float* __restrict__ out,
                                              const int* __restrict__ aidx,
                                              const float* __restrict__ fc1w,
                                              const float* __restrict__ fc1b,
                                              const float* __restrict__ fc2w,
                                              const float* __restrict__ fc2b,
                                              float* __restrict__ logits) {
  const int b = blockIdx.x;
  const int t = threadIdx.x;
  __shared__ float emb[A_][1024];
  __shared__ float h1[A_][256];
  __shared__ float sent[512];
  const float* ob = out + (size_t)b * W_ * 512;
  float s0 = 0.f, s1 = 0.f;
  for (int tt = 0; tt < W_; ++tt) {
    s0 += ob[tt * 512 + t];
    s1 += ob[tt * 512 + 256 + t];
  }
  sent[t] = s0 * (1.f / 256.f);
  sent[t + 256] = s1 * (1.f / 256.f);
  __syncthreads();
  for (int a = 0; a < A_; ++a) {
    int nv = 0;
    float m0 = 0.f, m1 = 0.f;
    for (int k = 0; k < KK_; ++k) {
      const int idx = aidx[(b * A_ + a) * KK_ + k];
      if (idx >= 0) {
        const int tt = min(idx, W_ - 2) + 1;
        m0 += ob[tt * 512 + t];
        m1 += ob[tt * 512 + 256 + t];
        nv++;
      }
    }
    const float inv = nv > 0 ? 1.f / (float)nv : 0.f;
    const bool valid = nv > 0;
    emb[a][t]        = valid ? sent[t] : 0.f;
    emb[a][t + 256]  = valid ? sent[t + 256] : 0.f;
    emb[a][512 + t]       = m0 * inv;
    emb[a][512 + 256 + t] = m1 * inv;
  }
  __syncthreads();
  {
    float acc[A_];
#pragma unroll
    for (int a = 0; a < A_; ++a) acc[a] = fc1b[t];
    const float* wrow = fc1w + (size_t)t * 1024;
    for (int j = 0; j < 1024; j += 4) {
      const float4 w = *(const float4*)(wrow + j);
#pragma unroll
      for (int a = 0; a < A_; ++a) {
        const float4 e = *(const float4*)(&emb[a][j]);
        acc[a] += w.x * e.x + w.y * e.y + w.z * e.z + w.w * e.w;
      }
    }
#pragma unroll
    for (int a = 0; a < A_; ++a) h1[a][t] = fmaxf(acc[a], 0.f);
  }
  __syncthreads();
  if (t < A_ * 4) {
    const int a = t >> 2, l = t & 3;
    float acc = fc2b[l];
    const float* w = fc2w + l * 256;
    for (int j = 0; j < 256; ++j) acc += w[j] * h1[a][j];
    logits[(b * A_ + a) * 4 + l] = acc;
  }
}

extern "C" void kernel_launch(void* const* d_in, const int* in_sizes, int n_in,
                              void* d_out, int out_size, void* d_ws, size_t ws_size,
                              hipStream_t stream) {
  const float* emb  = (const float*)d_in[0];
  const int*   mask = (const int*)d_in[1];
  const int*   aidx = (const int*)d_in[2];
  const float* wihf = (const float*)d_in[3];
  const float* whhf = (const float*)d_in[4];
  const float* bihf = (const float*)d_in[5];
  const float* bhhf = (const float*)d_in[6];
  const float* wihr = (const float*)d_in[7];
  const float* whhr = (const float*)d_in[8];
  const float* bihr = (const float*)d_in[9];
  const float* bhhr = (const float*)d_in[10];
  const float* fc1w = (const float*)d_in[11];
  const float* fc1b = (const float*)d_in[12];
  const float* fc2w = (const float*)d_in[13];
  const float* fc2b = (const float*)d_in[14];
  float* logits = (float*)d_out;

  char* ws = (char*)d_ws;
  size_t off = 0;
  auto alloc = [&](size_t bytes) -> void* {
    void* p = ws + off;
    off += (bytes + 255) & ~(size_t)255;
    return p;
  };
  __hip_bfloat16* words = (__hip_bfloat16*)alloc((size_t)M_ * D_ * 2);
  _Float16*       xg    = (_Float16*)alloc((size_t)M_ * N2 * 2);
  __hip_bfloat16* wih   = (__hip_bfloat16*)alloc((size_t)N2 * D_ * 2);
  float*          bias  = (float*)alloc((size_t)N2 * 4);
  h2_t*           whhP  = (h2_t*)alloc((size_t)2 * 128 * 1024 * 4);
  f32x4*          wstr  = (f32x4*)alloc((size_t)2 * 2 * NSC * 512 * 16);
  unsigned*       hx    = (unsigned*)alloc((size_t)256 * 64 * 4);
  int*            flg   = (int*)alloc((size_t)256 * 4);
  float*          outh  = (float*)alloc((size_t)B_ * W_ * 512 * 4);

  k_words<<<B_ * W_, 256, 0, stream>>>(emb, mask, words);
  k_prep_wih<<<(N2 * D_) / 256, 256, 0, stream>>>(wihf, wihr, bihf, bhhf, bihr, bhhr, wih, bias);
  k_prep_whh<<<(2 * 128 * 1024) / 256, 256, 0, stream>>>(whhf, whhr, whhP);
  k_prep_wstr<<<(2 * 2 * NSC * 512 + 255) / 256, 256, 0, stream>>>(whhP, wstr);
  k_zero_flags<<<1, 256, 0, stream>>>(flg);
  dim3 gg(N2 / 128, M_ / 128);
  k_gemm_xg<<<gg, 256, 0, stream>>>(words, wih, bias, xg);
  k_lstm<<<256, 512, 0, stream>>>(xg, whhP, wstr, hx, flg, outh);
  k_head<<<B_, 256, 0, stream>>>(outh, aidx, fc1w, fc1b, fc2w, fc2b, logits);
}

// Round 11
// 929.501 us; speedup vs baseline: 2.9638x; 2.9638x over previous
//
#include <hip/hip_runtime.h>
#include <hip/hip_bf16.h>
#include <hip/hip_fp16.h>
#include <math.h>

// Problem constants
#define B_   64
#define SWP  512
#define D_   768
#define W_   256     // NUM_WORDS
#define H_   256
#define G4   1024    // 4*H
#define N2   2048    // both dirs' gates
#define M_   16384   // B_*W_ rows
#define A_   8
#define KK_  4

typedef __attribute__((ext_vector_type(4))) float f32x4;
typedef __attribute__((ext_vector_type(2))) float f32x2;
typedef __attribute__((ext_vector_type(8))) short bf16x8;
typedef __attribute__((ext_vector_type(4))) unsigned u32x4;
typedef _Float16 __attribute__((ext_vector_type(2))) h2_t;

// k_lstm v11 weight tiers per gate row (128 h2 k-pairs):
//   pairs  0..23 : f16 in VGPRs (24/row x 2 rows = 48 regs; R9-proven clean)
//   pairs 24..55 : f16 in LDS (16 chunks x 512 x 16B = 128 KB; R7-proven)
//   pairs 56..127: e4m3 fp8 streamed (18 dwordx4/thread/step = 144 KB/blk/step)
#define PV 24
#define NG 9    // stream groups per row (8 pairs each)

__device__ __forceinline__ void gload_lds16(const void* g, void* l) {
  __builtin_amdgcn_global_load_lds((const __attribute__((address_space(1))) void*)g,
                                   (__attribute__((address_space(3))) void*)l, 16, 0, 0);
}

__device__ __forceinline__ float sigm(float x) { return 1.f / (1.f + __expf(-x)); }
__device__ __forceinline__ float tanh_(float x) { return 1.f - 2.f / (1.f + __expf(2.f * x)); }

__device__ __forceinline__ float dot2acc(h2_t w, h2_t h, float acc) {
#if __has_builtin(__builtin_amdgcn_fdot2)
  return __builtin_amdgcn_fdot2(w, h, acc, false);
#else
  return acc + (float)w[0] * (float)h[0] + (float)w[1] * (float)h[1];
#endif
}

__device__ __forceinline__ h2_t bc_h2(unsigned int v) {
  union { unsigned u; h2_t h; } c; c.u = v; return c.h;
}

// pack two exact f32 (e4m3-decoded) into f16 pair; pkrtz is exact here.
__device__ __forceinline__ h2_t pk16(float a, float b) {
  auto v = __builtin_amdgcn_cvt_pkrtz(a, b);
  union { decltype(v) x; h2_t h; } u; u.x = v; return u.h;
}

// software f32 -> OCP e4m3fn encoder (prep-time only)
__device__ unsigned enc_e4m3(float x) {
  if (x != x) return 0x7f;
  unsigned s = 0; if (x < 0.f) { s = 0x80; x = -x; }
  if (x >= 448.f) return s | 0x7e;
  if (x < 0.0009765625f) return s;           // < 2^-10 -> 0
  int e; float m = frexpf(x, &e);            // x = m*2^e, m in [0.5,1)
  int E = e + 6;
  if (E >= 1) {
    unsigned mant = (unsigned)rintf(m * 16.f - 8.f);
    if (mant == 8) { mant = 0; ++E; }
    if (E > 15 || (E == 15 && mant == 7)) return s | 0x7e;
    return s | ((unsigned)E << 3) | mant;
  } else {
    unsigned dm = (unsigned)rintf(x * 512.f);
    if (dm >= 8) return s | 0x08;
    return s | dm;
  }
}

// K1: scatter-mean wordpieces -> words (bf16). One block per (b, word).
__global__ __launch_bounds__(256) void k_words(const float* __restrict__ emb,
                                               const int* __restrict__ mask,
                                               __hip_bfloat16* __restrict__ words) {
  const int b = blockIdx.x >> 8;
  const int w = blockIdx.x & 255;
  const int tid = threadIdx.x;
  __shared__ int m[SWP];
  m[tid] = mask[b * SWP + tid];
  m[tid + 256] = mask[b * SWP + 256 + tid];
  __syncthreads();
  int lo = 0, hi = SWP;
  while (lo < hi) { int mid = (lo + hi) >> 1; if (m[mid] < w) lo = mid + 1; else hi = mid; }
  int lo2 = lo, hi2 = SWP;
  while (lo2 < hi2) { int mid = (lo2 + hi2) >> 1; if (m[mid] < w + 1) lo2 = mid + 1; else hi2 = mid; }
  const int cnt = lo2 - lo;
  const float inv = (cnt > 0) ? 1.f / (float)cnt : 0.f;
  float s0 = 0.f, s1 = 0.f, s2 = 0.f;
  for (int s = lo; s < lo2; ++s) {
    const float* row = emb + ((size_t)b * SWP + s) * D_;
    s0 += row[tid]; s1 += row[tid + 256]; s2 += row[tid + 512];
  }
  __hip_bfloat16* o = words + ((size_t)b * W_ + w) * D_;
  o[tid]       = __float2bfloat16(s0 * inv);
  o[tid + 256] = __float2bfloat16(s1 * inv);
  o[tid + 512] = __float2bfloat16(s2 * inv);
}

// K2a: concat+convert input weights to bf16 [2048][768]; fused bias [2048]
__global__ __launch_bounds__(256) void k_prep_wih(const float* __restrict__ wf, const float* __restrict__ wr,
                                                  const float* __restrict__ bihf, const float* __restrict__ bhhf,
                                                  const float* __restrict__ bihr, const float* __restrict__ bhhr,
                                                  __hip_bfloat16* __restrict__ wih, float* __restrict__ bias) {
  const int i = blockIdx.x * 256 + threadIdx.x;
  const int n = i / D_;
  const int k = i - n * D_;
  const float v = (n < G4) ? wf[n * D_ + k] : wr[(n - G4) * D_ + k];
  wih[i] = __float2bfloat16(v);
  if (i < N2) {
    bias[i] = (i < G4) ? (bihf[i] + bhhf[i]) : (bihr[i - G4] + bhhr[i - G4]);
  }
}

// K2b: repack w_hh as half2 [dir][128 kk][1024 r]
__global__ __launch_bounds__(256) void k_prep_whh(const float* __restrict__ whf,
                                                  const float* __restrict__ whr,
                                                  h2_t* __restrict__ whhP) {
  const int i = blockIdx.x * 256 + threadIdx.x;   // 2*128*1024
  const int d = i >> 17;
  const int kk = (i >> 10) & 127;
  const int r = i & 1023;
  const float* w = d ? whr : whf;
  h2_t v;
  v[0] = (_Float16)w[r * H_ + 2 * kk];
  v[1] = (_Float16)w[r * H_ + 2 * kk + 1];
  whhP[i] = v;
}

// K2c: pack stream tier as e4m3. wstr8[d][c][t] (uint4 = 16 bytes = 8 pairs):
//   c in 0..17; c<9 -> row r1(t), else r2(t); pairs ps=56+8*(c%9) .. ps+7.
//   u32 q: bytes = (pair ps+2q elem0, elem1, pair ps+2q+1 elem0, elem1)
__global__ __launch_bounds__(256) void k_prep_wstr8(const h2_t* __restrict__ whhP,
                                                    u32x4* __restrict__ wstr8) {
  const int i = blockIdx.x * 256 + threadIdx.x;   // 2*18*512
  if (i >= 2 * 2 * NG * 512) return;
  const int t = i & 511;
  const int c = (i >> 9) % (2 * NG);
  const int d = i / (2 * NG * 512);
  const int u = t & 255;
  const int r1 = (t < 256) ? u : (256 + u);
  const int row = (c < NG) ? r1 : (r1 + 512);
  const int ps = 56 + 8 * (c % NG);
  const h2_t* wp = whhP + (size_t)d * (128 * 1024);
  u32x4 out;
#pragma unroll
  for (int q = 0; q < 4; ++q) {
    const h2_t p0 = wp[(ps + 2 * q) * 1024 + row];
    const h2_t p1 = wp[(ps + 2 * q + 1) * 1024 + row];
    out[q] = enc_e4m3((float)p0[0]) | (enc_e4m3((float)p0[1]) << 8)
           | (enc_e4m3((float)p1[0]) << 16) | (enc_e4m3((float)p1[1]) << 24);
  }
  wstr8[i] = out;
}

// K3: xg = words @ W_ih^T + bias, bf16 MFMA, 128x128 tile, out f16
__global__ __launch_bounds__(256) void k_gemm_xg(const __hip_bfloat16* __restrict__ A,
                                                 const __hip_bfloat16* __restrict__ Wt,
                                                 const float* __restrict__ bias,
                                                 _Float16* __restrict__ C) {
  const int bm = blockIdx.y * 128;
  const int bn = blockIdx.x * 128;
  __shared__ __hip_bfloat16 As[128 * 32];
  __shared__ __hip_bfloat16 Bs[128 * 32];
  const int tid = threadIdx.x;
  const int lane = tid & 63;
  const int wave = tid >> 6;
  const int wm = (wave >> 1) * 64;
  const int wn = (wave & 1) * 64;
  const int l15 = lane & 15;
  const int l4 = lane >> 4;
  const int row_a = tid >> 2;
  const int chunk = tid & 3;
  f32x4 acc[4][4] = {};
  for (int k0 = 0; k0 < D_; k0 += 32) {
    const __hip_bfloat16* ga  = A  + (size_t)(bm + row_a) * D_ + k0 + chunk * 8;
    const __hip_bfloat16* ga2 = A  + (size_t)(bm + 64 + row_a) * D_ + k0 + chunk * 8;
    const __hip_bfloat16* gb  = Wt + (size_t)(bn + row_a) * D_ + k0 + chunk * 8;
    const __hip_bfloat16* gb2 = Wt + (size_t)(bn + 64 + row_a) * D_ + k0 + chunk * 8;
    gload_lds16(ga,  As + tid * 8);
    gload_lds16(ga2, As + 2048 + tid * 8);
    gload_lds16(gb,  Bs + tid * 8);
    gload_lds16(gb2, Bs + 2048 + tid * 8);
    __syncthreads();
    bf16x8 af[4], bf[4];
#pragma unroll
    for (int i = 0; i < 4; ++i) {
      af[i] = *(const bf16x8*)(As + (wm + i * 16 + l15) * 32 + l4 * 8);
      bf[i] = *(const bf16x8*)(Bs + (wn + i * 16 + l15) * 32 + l4 * 8);
    }
#pragma unroll
    for (int i = 0; i < 4; ++i)
#pragma unroll
      for (int j = 0; j < 4; ++j)
        acc[i][j] = __builtin_amdgcn_mfma_f32_16x16x32_bf16(af[i], bf[j], acc[i][j], 0, 0, 0);
    __syncthreads();
  }
#pragma unroll
  for (int i = 0; i < 4; ++i) {
    const int m = bm + wm + i * 16 + l4 * 4;
#pragma unroll
    for (int j = 0; j < 4; ++j) {
      const int n = bn + wn + j * 16 + l15;
      const float bs = bias[n];
#pragma unroll
      for (int r = 0; r < 4; ++r)
        C[(size_t)(m + r) * N2 + n] = (_Float16)(acc[i][j][r] + bs);
    }
  }
}

// K4 v11: three-tier (VGPR f16 24 / LDS f16 32 / streamed e4m3 72 pairs/row).
// Block = (dir, batch), 512 threads. Thread t: rows r1 (i|f), r2 = r1+512 (g|o).
// h broadcast via readlane; stream loads double-buffered with f16-tier cover.
__global__ __launch_bounds__(512)
void k_lstm(const _Float16* __restrict__ xg,     // [M_][2048]
            const h2_t* __restrict__ whhP,       // [2][128][1024]
            const u32x4* __restrict__ wstr8,     // [2][18][512]
            float* __restrict__ out) {           // [B_][W_][512]
  const int bx = blockIdx.x;
  const int d = bx & 1;
  const int b = bx >> 1;
  const int t = threadIdx.x;
  const int u = t & 255;
  const int l = t & 63;
  const bool low = (t < 256);
  const int r1 = low ? u : (256 + u);
  const int r2 = r1 + 512;

  __shared__ __align__(16) _Float16 hbuf[256];      // 128 h2 pairs
  __shared__ __align__(16) h2_t wlds[16][512][4];   // 128 KB: pairs 24..55
  __shared__ float fo[256][2];

  const h2_t* wp = whhP + (size_t)d * (128 * 1024);
  const u32x4* wsp = wstr8 + (size_t)d * (2 * NG * 512);

  // VGPR tier: pairs 0..23 of both rows (48 regs)
  unsigned wv1[PV], wv2[PV];
#pragma unroll
  for (int j = 0; j < PV; ++j) {
    wv1[j] = *(const unsigned*)&wp[j * 1024 + r1];
    wv2[j] = *(const unsigned*)&wp[j * 1024 + r2];
  }
  // LDS tier: pairs 24..55. chunk c<8 -> row r1, c>=8 -> row r2.
#pragma unroll
  for (int c = 0; c < 16; ++c) {
    const int row = (c < 8) ? r1 : r2;
    const int kb = PV + (c & 7) * 4;
    f32x4 v;
#pragma unroll
    for (int q = 0; q < 4; ++q)
      ((h2_t*)&v)[q] = wp[(kb + q) * 1024 + row];
    *(f32x4*)&wlds[c][t][0] = v;
  }
  if (t < 256) hbuf[t] = (_Float16)0.f;
  __syncthreads();

  float c_state = 0.f;
#pragma unroll 1
  for (int step = 0; step < W_; ++step) {
    const int tt = d ? (W_ - 1 - step) : step;
    const _Float16* xrow = xg + ((size_t)b * W_ + tt) * N2 + d * G4;
    const float xv1 = (float)xrow[r1];
    const float xv2 = (float)xrow[r2];
    float a1a = 0.f, a1b = 0.f, a2a = 0.f, a2b = 0.f;
    if (step > 0) {
      // prologue: issue stream group 0 (both rows)
      u32x4 sb1[2], sb2[2];
      sb1[0] = wsp[0 * 512 + t];
      sb2[0] = wsp[NG * 512 + t];
      // per-lane h slices: lane l holds pair l (hA), pair 64+l (hB)
      const unsigned hA = *(const unsigned*)&hbuf[2 * l];
      const unsigned hB = *(const unsigned*)&hbuf[128 + 2 * l];
      // ---- VGPR tier: pairs 0..23 (covers stream latency) ----
#pragma unroll
      for (int j = 0; j < PV; ++j) {
        const h2_t hq = bc_h2(__builtin_amdgcn_readlane(hA, j));
        if (j & 1) { a1b = dot2acc(bc_h2(wv1[j]), hq, a1b); a2b = dot2acc(bc_h2(wv2[j]), hq, a2b); }
        else       { a1a = dot2acc(bc_h2(wv1[j]), hq, a1a); a2a = dot2acc(bc_h2(wv2[j]), hq, a2a); }
      }
      // ---- LDS tier: pairs 24..55 ----
#pragma unroll
      for (int c = 0; c < 8; ++c) {
        const f32x4 w1 = *(const f32x4*)&wlds[c][t][0];
        const f32x4 w2 = *(const f32x4*)&wlds[8 + c][t][0];
        const h2_t* p1 = (const h2_t*)&w1;
        const h2_t* p2 = (const h2_t*)&w2;
#pragma unroll
        for (int q = 0; q < 4; ++q) {
          const int p = PV + 4 * c + q;
          const h2_t hq = bc_h2(__builtin_amdgcn_readlane(hA, p));
          if (q & 1) { a1b = dot2acc(p1[q], hq, a1b); a2b = dot2acc(p2[q], hq, a2b); }
          else       { a1a = dot2acc(p1[q], hq, a1a); a2a = dot2acc(p2[q], hq, a2a); }
        }
      }
      // ---- stream tier: pairs 56..127, e4m3, 9 groups x 8 pairs, dbuf ----
#pragma unroll
      for (int g = 0; g < NG; ++g) {
        if (g + 1 < NG) {
          sb1[(g + 1) & 1] = wsp[(g + 1) * 512 + t];
          sb2[(g + 1) & 1] = wsp[(NG + g + 1) * 512 + t];
        }
        const u32x4 s1 = sb1[g & 1];
        const u32x4 s2 = sb2[g & 1];
        const int ps = 56 + 8 * g;
#pragma unroll
        for (int q = 0; q < 4; ++q) {
          // wsel = 0 (low word -> pair ps+2q)
          {
            const int p = ps + 2 * q;
            const unsigned hv = (p < 64) ? __builtin_amdgcn_readlane(hA, p)
                                         : __builtin_amdgcn_readlane(hB, p - 64);
            const h2_t hq = bc_h2(hv);
            const f32x2 f1 = __builtin_amdgcn_cvt_pk_f32_fp8((int)s1[q], false);
            const f32x2 f2 = __builtin_amdgcn_cvt_pk_f32_fp8((int)s2[q], false);
            a1a = dot2acc(pk16(f1[0], f1[1]), hq, a1a);
            a2a = dot2acc(pk16(f2[0], f2[1]), hq, a2a);
          }
          // wsel = 1 (high word -> pair ps+2q+1)
          {
            const int p = ps + 2 * q + 1;
            const unsigned hv = (p < 64) ? __builtin_amdgcn_readlane(hA, p)
                                         : __builtin_amdgcn_readlane(hB, p - 64);
            const h2_t hq = bc_h2(hv);
            const f32x2 f1 = __builtin_amdgcn_cvt_pk_f32_fp8((int)s1[q], true);
            const f32x2 f2 = __builtin_amdgcn_cvt_pk_f32_fp8((int)s2[q], true);
            a1b = dot2acc(pk16(f1[0], f1[1]), hq, a1b);
            a2b = dot2acc(pk16(f2[0], f2[1]), hq, a2b);
          }
        }
      }
    }
    const float a1 = a1a + a1b + xv1;
    const float a2 = a2a + a2b + xv2;
    if (!low) { fo[u][0] = a1; fo[u][1] = a2; }
    __syncthreads();
    if (low) {
      const float ig = sigm(a1);
      const float gg = tanh_(a2);
      const float fg = sigm(fo[u][0]);
      const float og = sigm(fo[u][1]);
      c_state = fg * c_state + ig * gg;
      const float h = og * tanh_(c_state);
      out[((size_t)b * W_ + tt) * 512 + d * 256 + u] = h;
      hbuf[u] = (_Float16)h;
    }
    __syncthreads();
  }
}

// K5: sent-mean + aspect gather-mean + fc1(relu) + fc2. One block per batch.
__global__ __launch_bounds__(256) void k_head(const float* __restrict__ out,
                                              const int* __restrict__ aidx,
                                              const float* __restrict__ fc1w,
                                              const float* __restrict__ fc1b,
                                              const float* __restrict__ fc2w,
                                              const float* __restrict__ fc2b,
                                              float* __restrict__ logits) {
  const int b = blockIdx.x;
  const int t = threadIdx.x;
  __shared__ float emb[A_][1024];
  __shared__ float h1[A_][256];
  __shared__ float sent[512];
  const float* ob = out + (size_t)b * W_ * 512;
  float s0 = 0.f, s1 = 0.f;
  for (int tt = 0; tt < W_; ++tt) {
    s0 += ob[tt * 512 + t];
    s1 += ob[tt * 512 + 256 + t];
  }
  sent[t] = s0 * (1.f / 256.f);
  sent[t + 256] = s1 * (1.f / 256.f);
  __syncthreads();
  for (int a = 0; a < A_; ++a) {
    int nv = 0;
    float m0 = 0.f, m1 = 0.f;
    for (int k = 0; k < KK_; ++k) {
      const int idx = aidx[(b * A_ + a) * KK_ + k];
      if (idx >= 0) {
        const int tt = min(idx, W_ - 2) + 1;
        m0 += ob[tt * 512 + t];
        m1 += ob[tt * 512 + 256 + t];
        nv++;
      }
    }
    const float inv = nv > 0 ? 1.f / (float)nv : 0.f;
    const bool valid = nv > 0;
    emb[a][t]        = valid ? sent[t] : 0.f;
    emb[a][t + 256]  = valid ? sent[t + 256] : 0.f;
    emb[a][512 + t]       = m0 * inv;
    emb[a][512 + 256 + t] = m1 * inv;
  }
  __syncthreads();
  {
    float acc[A_];
#pragma unroll
    for (int a = 0; a < A_; ++a) acc[a] = fc1b[t];
    const float* wrow = fc1w + (size_t)t * 1024;
    for (int j = 0; j < 1024; j += 4) {
      const float4 w = *(const float4*)(wrow + j);
#pragma unroll
      for (int a = 0; a < A_; ++a) {
        const float4 e = *(const float4*)(&emb[a][j]);
        acc[a] += w.x * e.x + w.y * e.y + w.z * e.z + w.w * e.w;
      }
    }
#pragma unroll
    for (int a = 0; a < A_; ++a) h1[a][t] = fmaxf(acc[a], 0.f);
  }
  __syncthreads();
  if (t < A_ * 4) {
    const int a = t >> 2, l = t & 3;
    float acc = fc2b[l];
    const float* w = fc2w + l * 256;
    for (int j = 0; j < 256; ++j) acc += w[j] * h1[a][j];
    logits[(b * A_ + a) * 4 + l] = acc;
  }
}

extern "C" void kernel_launch(void* const* d_in, const int* in_sizes, int n_in,
                              void* d_out, int out_size, void* d_ws, size_t ws_size,
                              hipStream_t stream) {
  const float* emb  = (const float*)d_in[0];
  const int*   mask = (const int*)d_in[1];
  const int*   aidx = (const int*)d_in[2];
  const float* wihf = (const float*)d_in[3];
  const float* whhf = (const float*)d_in[4];
  const float* bihf = (const float*)d_in[5];
  const float* bhhf = (const float*)d_in[6];
  const float* wihr = (const float*)d_in[7];
  const float* whhr = (const float*)d_in[8];
  const float* bihr = (const float*)d_in[9];
  const float* bhhr = (const float*)d_in[10];
  const float* fc1w = (const float*)d_in[11];
  const float* fc1b = (const float*)d_in[12];
  const float* fc2w = (const float*)d_in[13];
  const float* fc2b = (const float*)d_in[14];
  float* logits = (float*)d_out;

  char* ws = (char*)d_ws;
  size_t off = 0;
  auto alloc = [&](size_t bytes) -> void* {
    void* p = ws + off;
    off += (bytes + 255) & ~(size_t)255;
    return p;
  };
  __hip_bfloat16* words = (__hip_bfloat16*)alloc((size_t)M_ * D_ * 2);
  _Float16*       xg    = (_Float16*)alloc((size_t)M_ * N2 * 2);
  __hip_bfloat16* wih   = (__hip_bfloat16*)alloc((size_t)N2 * D_ * 2);
  float*          bias  = (float*)alloc((size_t)N2 * 4);
  h2_t*           whhP  = (h2_t*)alloc((size_t)2 * 128 * 1024 * 4);
  u32x4*          wstr8 = (u32x4*)alloc((size_t)2 * 2 * NG * 512 * 16);
  float*          outh  = (float*)alloc((size_t)B_ * W_ * 512 * 4);

  k_words<<<B_ * W_, 256, 0, stream>>>(emb, mask, words);
  k_prep_wih<<<(N2 * D_) / 256, 256, 0, stream>>>(wihf, wihr, bihf, bhhf, bihr, bhhr, wih, bias);
  k_prep_whh<<<(2 * 128 * 1024) / 256, 256, 0, stream>>>(whhf, whhr, whhP);
  k_prep_wstr8<<<(2 * 2 * NG * 512 + 255) / 256, 256, 0, stream>>>(whhP, wstr8);
  dim3 gg(N2 / 128, M_ / 128);
  k_gemm_xg<<<gg, 256, 0, stream>>>(words, wih, bias, xg);
  k_lstm<<<B_ * 2, 512, 0, stream>>>(xg, whhP, wstr8, outh);
  k_head<<<B_, 256, 0, stream>>>(outh, aidx, fc1w, fc1b, fc2w, fc2b, logits);
}